// Round 10
// baseline (61.617 us; speedup 1.0000x reference)
//
#include <hip/hip_runtime.h>
#include <hip/hip_bf16.h>
#include <stdint.h>

// RNDiscriminator: B=64, d^2=64 positions, 26 features, g: 52->256->256, f: 256->1
// h1[i,j] = relu(u'[j] + v[i]); dominant cost sum_ij relu(h1 @ W2 + b2) = 34.4 GF bf16.
//
// k3 (R10): 256 blocks x 512 thr (8 waves, 1 block/CU). u-tile resident in
// registers (32 f32/thread); zero global loads in the 16-pair loop. Wave wv owns
// a 32x64 C-quadrant (r0=(wv&1)*32, c0=(wv>>1)*64): Bf[8][4]=128 VGPR, acc[2][4].
// Per-pair LDS reads = 128 KB (4-way A-reuse) < per-SIMD MFMA time -> MFMA-bound.
// h1 double-buffered (2x32KB LDS, XOR-swizzled b128). One barrier per pair.

typedef float f32x4 __attribute__((ext_vector_type(4)));
typedef float f32x2 __attribute__((ext_vector_type(2)));
typedef short short8 __attribute__((ext_vector_type(8)));
typedef int   int4v  __attribute__((ext_vector_type(4)));

__device__ __forceinline__ uint32_t cvt_pk_bf16(float lo, float hi) {
    uint32_t r;
    asm("v_cvt_pk_bf16_f32 %0, %1, %2" : "=v"(r) : "v"(lo), "v"(hi));
    return r;
}
__device__ __forceinline__ f32x2 relu2(f32x2 a) {
    f32x2 z = (f32x2){0.f, 0.f};
    return __builtin_elementwise_max(a, z);
}

// K12: blocks 0..255: fused conv(8x8/s8)+relu+coords -> u,v rows.
//      blocks 256..287: pre-fragment W2 (bf16, fragment-major).
__global__ void k12_front(const float* __restrict__ img, const float* __restrict__ cw,
                          const float* __restrict__ cb, const float* __restrict__ w1,
                          const float* __restrict__ b1, const float* __restrict__ w2,
                          float* __restrict__ u, float* __restrict__ v,
                          short* __restrict__ w2f) {
    int g = blockIdx.x;
    int t = threadIdx.x;
    if (g >= 256) {
        int fi = (g - 256) * 4 + (t >> 6);
        int l = t & 63;
        int ks = fi >> 4, ni2 = fi & 15;
        int n  = ni2 * 16 + (l & 15);
        int k0 = ks * 32 + (l >> 4) * 8;
        float f[8];
        #pragma unroll
        for (int e = 0; e < 8; ++e) f[e] = w2[(k0 + e) * 256 + n];
        union { short8 s; uint32_t w[4]; } A;
        A.w[0] = cvt_pk_bf16(f[0], f[1]);
        A.w[1] = cvt_pk_bf16(f[2], f[3]);
        A.w[2] = cvt_pk_bf16(f[4], f[5]);
        A.w[3] = cvt_pk_bf16(f[6], f[7]);
        *(short8*)(w2f + (fi * 64 + l) * 8) = A.s;
        return;
    }
    __shared__ float xs[16][26];
    int b = g >> 2, q = g & 3, p0 = q * 16;

    for (int idx = t; idx < 416; idx += 256) {
        int pl = idx / 26;
        int ch = idx - pl * 26;
        int pos = p0 + pl;
        int r = pos >> 3, c = pos & 7;
        float val;
        if (ch < 24) {
            float s = cb[ch];
            #pragma unroll
            for (int ci = 0; ci < 3; ++ci)
                #pragma unroll
                for (int kr = 0; kr < 8; ++kr) {
                    const float* ip = img + ((b * 3 + ci) * 64 + r * 8 + kr) * 64 + c * 8;
                    const float* wp = cw + ((ch * 3 + ci) * 8 + kr) * 8;
                    #pragma unroll
                    for (int kc = 0; kc < 8; ++kc) s += ip[kc] * wp[kc];
                }
            val = fmaxf(s, 0.f);
        } else if (ch == 24) {
            val = -1.f + (2.f / 7.f) * (float)c;
        } else {
            val = -1.f + (2.f / 7.f) * (float)r;
        }
        xs[pl][ch] = val;
    }
    __syncthreads();

    // phase 2, k-outer (w1 loads hoisted)
    int c = t;
    float bc = b1[c];
    float su[16], sv[16];
    #pragma unroll
    for (int r = 0; r < 16; ++r) { su[r] = bc; sv[r] = 0.f; }
    #pragma unroll 2
    for (int k = 0; k < 26; ++k) {
        float wu = w1[k * 256 + c];
        float wv2 = w1[(26 + k) * 256 + c];
        #pragma unroll
        for (int r = 0; r < 16; ++r) {
            float xv = xs[r][k];
            su[r] += xv * wu;
            sv[r] += xv * wv2;
        }
    }
    #pragma unroll
    for (int r = 0; r < 16; ++r) {
        int bj = b * 64 + p0 + r;
        u[bj * 256 + c] = su[r];
        v[bj * 256 + c] = sv[r];
    }
}

// ---- k3 macros ----
// STAGE(Q, BUF): rows rq*4+rr, cols col8*8..+8 from u-registers + vs[Q];
// one ds_write_b128 per row at precomputed swizzled offset wb[rr].
#define STAGE(Q, BUF)                                                  \
{                                                                      \
    f32x4 va = *(const f32x4*)&vs[Q][col8 * 8];                        \
    f32x4 vb = *(const f32x4*)&vs[Q][col8 * 8 + 4];                    \
    _Pragma("unroll")                                                  \
    for (int rr = 0; rr < 4; ++rr) {                                   \
        f32x2 a0 = relu2((f32x2){u0[rr].x, u0[rr].y} + (f32x2){va.x, va.y}); \
        f32x2 a1 = relu2((f32x2){u0[rr].z, u0[rr].w} + (f32x2){va.z, va.w}); \
        f32x2 a2 = relu2((f32x2){u1[rr].x, u1[rr].y} + (f32x2){vb.x, vb.y}); \
        f32x2 a3 = relu2((f32x2){u1[rr].z, u1[rr].w} + (f32x2){vb.z, vb.w}); \
        int4v d;                                                       \
        d.x = (int)cvt_pk_bf16(a0.x, a0.y);                            \
        d.y = (int)cvt_pk_bf16(a1.x, a1.y);                            \
        d.z = (int)cvt_pk_bf16(a2.x, a2.y);                            \
        d.w = (int)cvt_pk_bf16(a3.x, a3.y);                            \
        *(int4v*)((char*)(BUF) + wb[rr]) = d;                          \
    }                                                                  \
}

// A-frag read: (row = r0 + mi*16 + lr, k0 = ks*32+lg*8) at byte
// (r0+lr)*512 + mi*8192 + (ks>>1)*128 + (XB or XB^64), XB = (lg*16)^((lr&7)<<4).
#define MFMA_KS(KS)                                                   \
    { const char* hx = ((KS) & 1) ? hO : hE;                          \
      short8 a0 = *(const short8*)(hx + ((KS) >> 1) * 128);           \
      short8 a1 = *(const short8*)(hx + 8192 + ((KS) >> 1) * 128);    \
      acc[0][0] = __builtin_amdgcn_mfma_f32_16x16x32_bf16(a0, Bf[KS][0], acc[0][0], 0, 0, 0); \
      acc[1][0] = __builtin_amdgcn_mfma_f32_16x16x32_bf16(a1, Bf[KS][0], acc[1][0], 0, 0, 0); \
      acc[0][1] = __builtin_amdgcn_mfma_f32_16x16x32_bf16(a0, Bf[KS][1], acc[0][1], 0, 0, 0); \
      acc[1][1] = __builtin_amdgcn_mfma_f32_16x16x32_bf16(a1, Bf[KS][1], acc[1][1], 0, 0, 0); \
      acc[0][2] = __builtin_amdgcn_mfma_f32_16x16x32_bf16(a0, Bf[KS][2], acc[0][2], 0, 0, 0); \
      acc[1][2] = __builtin_amdgcn_mfma_f32_16x16x32_bf16(a1, Bf[KS][2], acc[1][2], 0, 0, 0); \
      acc[0][3] = __builtin_amdgcn_mfma_f32_16x16x32_bf16(a0, Bf[KS][3], acc[0][3], 0, 0, 0); \
      acc[1][3] = __builtin_amdgcn_mfma_f32_16x16x32_bf16(a1, Bf[KS][3], acc[1][3], 0, 0, 0); }

__global__ __launch_bounds__(512, 2) void k3_pairs(
        const float* __restrict__ u, const float* __restrict__ v,
        const short* __restrict__ w2f, const float* __restrict__ b2,
        float* __restrict__ part) {
    __shared__ short h1s[2][64 * 256];   // 64 KB
    __shared__ float vs[16][256];        // 16 KB
    int t = threadIdx.x;
    int lane = t & 63, wv = t >> 6;      // wv 0..7
    int lr = lane & 15, lg = lane >> 4;
    int blk = blockIdx.x;                // 0..255
    int b = blk & 63, i0 = (blk >> 6) * 16;
    int r0 = (wv & 1) * 32;              // row half of C
    int c0 = (wv >> 1) * 64;             // col quarter of C

    // stage the 16 v rows once (vs[q][c]), 8 floats/thread
    {
        int q = t >> 5, c8 = (t & 31) * 8;
        const float* vr = v + (b * 64 + i0 + q) * 256 + c8;
        *(float4*)&vs[q][c8]     = *(const float4*)vr;
        *(float4*)&vs[q][c8 + 4] = *(const float4*)(vr + 4);
    }

    // resident B fragments: cols c0 + cg*16 (static indices only -- rule #20)
    short8 Bf[8][4];
    #pragma unroll
    for (int ks = 0; ks < 8; ++ks)
        #pragma unroll
        for (int cg = 0; cg < 4; ++cg)
            Bf[ks][cg] = *(const short8*)(w2f + ((ks * 16 + (wv >> 1) * 4 + cg) * 64 + lane) * 8);

    f32x2 bias2[4];
    #pragma unroll
    for (int cg = 0; cg < 4; ++cg) {
        float bv = b2[c0 + cg * 16 + lr];
        bias2[cg] = (f32x2){bv, bv};
    }

    // u residency: thread (col8 = t&31, rq = t>>5) holds rows rq*4..+4,
    // cols col8*8..+8 as f32 (32 VGPR)
    int col8 = t & 31, rq = t >> 5;
    const float* up = u + (b * 64 + rq * 4) * 256 + col8 * 8;
    f32x4 u0[4], u1[4];
    int wb[4];
    #pragma unroll
    for (int rr = 0; rr < 4; ++rr) {
        u0[rr] = *(const f32x4*)(up + rr * 256);
        u1[rr] = *(const f32x4*)(up + rr * 256 + 4);
        int row = rq * 4 + rr;
        wb[rr] = row * 512 + ((col8 * 16) ^ ((row & 7) << 4));
    }

    // read geometry
    int XB = (lg * 16) ^ ((lr & 7) << 4);
    int rE = (r0 + lr) * 512 + XB;
    int rO = (r0 + lr) * 512 + (XB ^ 64);

    __syncthreads();            // vs ready
    STAGE(0, h1s[0])
    __syncthreads();            // buf0 ready

    f32x2 csum2[4];
    #pragma unroll
    for (int cg = 0; cg < 4; ++cg) csum2[cg] = (f32x2){0.f, 0.f};

    #pragma unroll 1
    for (int q = 0; q < 16; ++q) {
        if (q < 15) STAGE(q + 1, h1s[(q + 1) & 1])

        const char* hE = (const char*)h1s[q & 1] + rE;
        const char* hO = (const char*)h1s[q & 1] + rO;

        f32x4 acc[2][4];
        #pragma unroll
        for (int mi = 0; mi < 2; ++mi)
            #pragma unroll
            for (int cg = 0; cg < 4; ++cg) acc[mi][cg] = (f32x4){0.f, 0.f, 0.f, 0.f};

        __builtin_amdgcn_s_setprio(1);
        MFMA_KS(0) MFMA_KS(1) MFMA_KS(2) MFMA_KS(3)
        MFMA_KS(4) MFMA_KS(5) MFMA_KS(6) MFMA_KS(7)
        __builtin_amdgcn_s_setprio(0);

        // epilogue: relu(C + b2) partial column-sum (packed)
        #pragma unroll
        for (int cg = 0; cg < 4; ++cg) {
            #pragma unroll
            for (int mi = 0; mi < 2; ++mi) {
                f32x2 lo = relu2((f32x2){acc[mi][cg].x, acc[mi][cg].y} + bias2[cg]);
                f32x2 hi = relu2((f32x2){acc[mi][cg].z, acc[mi][cg].w} + bias2[cg]);
                csum2[cg] = csum2[cg] + lo + hi;
            }
        }
        __syncthreads();
    }

    // flush: reduce over lg groups; lanes 0-15 store this wave's 64-col partial
    #pragma unroll
    for (int cg = 0; cg < 4; ++cg) {
        float s = csum2[cg].x + csum2[cg].y;
        s += __shfl_xor(s, 16);
        s += __shfl_xor(s, 32);
        if (lane < 16) part[(blk * 8 + wv) * 64 + cg * 16 + lr] = s;
    }
}

// K5: pooled[b][c] = sum over 4 tiles x 2 row-half waves; then f-head.
__global__ void k5_head(const float* __restrict__ part, const float* __restrict__ fw1,
                        const float* __restrict__ fb1, const float* __restrict__ fw2,
                        const float* __restrict__ fb2, float* __restrict__ out) {
    __shared__ float P[256];
    __shared__ float wsum[4];
    int b = blockIdx.x, t = threadIdx.x;
    int wpair = (t >> 6) * 2, cl = t & 63;
    float s0 = 0.f;
    #pragma unroll
    for (int tile = 0; tile < 4; ++tile) {
        const float* p = part + (((b + 64 * tile) * 8) + wpair) * 64 + cl;
        s0 += p[0] + p[64];
    }
    P[t] = s0;
    __syncthreads();
    float a0 = 0.f, a1 = 0.f, a2 = 0.f, a3 = 0.f;
    for (int k = 0; k < 64; ++k) {
        a0 += P[k]       * fw1[k * 256 + t];
        a1 += P[k + 64]  * fw1[(k + 64) * 256 + t];
        a2 += P[k + 128] * fw1[(k + 128) * 256 + t];
        a3 += P[k + 192] * fw1[(k + 192) * 256 + t];
    }
    float h = fmaxf(fb1[t] + a0 + a1 + a2 + a3, 0.f);
    float p = h * fw2[t];
    #pragma unroll
    for (int off = 32; off >= 1; off >>= 1) p += __shfl_xor(p, off);
    if ((t & 63) == 0) wsum[t >> 6] = p;
    __syncthreads();
    if (t == 0) out[b] = wsum[0] + wsum[1] + wsum[2] + wsum[3] + fb2[0];
}

extern "C" void kernel_launch(void* const* d_in, const int* in_sizes, int n_in,
                              void* d_out, int out_size, void* d_ws, size_t ws_size,
                              hipStream_t stream) {
    const float* image  = (const float*)d_in[0];
    const float* conv_w = (const float*)d_in[1];
    const float* conv_b = (const float*)d_in[2];
    const float* g_w1   = (const float*)d_in[3];
    const float* g_b1   = (const float*)d_in[4];
    const float* g_w2   = (const float*)d_in[5];
    const float* g_b2   = (const float*)d_in[6];
    const float* f_w1   = (const float*)d_in[7];
    const float* f_b1   = (const float*)d_in[8];
    const float* f_w2   = (const float*)d_in[9];
    const float* f_b2   = (const float*)d_in[10];
    float* out = (float*)d_out;

    char* ws = (char*)d_ws;
    float* u    = (float*)(ws + 0);          // 64*64*256*4 = 4 MB
    float* v    = (float*)(ws + 4194304);    // 4 MB
    short* w2f  = (short*)(ws + 8388608);    // 128 KB
    float* part = (float*)(ws + 8519680);    // 256*8*64*4 = 512 KB

    k12_front<<<288, 256, 0, stream>>>(image, conv_w, conv_b, g_w1, g_b1, g_w2,
                                       u, v, w2f);
    k3_pairs<<<256, 512, 0, stream>>>(u, v, w2f, g_b2, part);
    k5_head<<<64, 256, 0, stream>>>(part, f_w1, f_b1, f_w2, f_b2, out);
}

// Round 11
// 61.035 us; speedup vs baseline: 1.0095x; 1.0095x over previous
//
#include <hip/hip_runtime.h>
#include <hip/hip_bf16.h>
#include <stdint.h>

// RNDiscriminator: B=64, d^2=64 positions, 26 features, g: 52->256->256, f: 256->1
// h1[i,j] = relu(u'[j] + v[i]); dominant cost sum_ij relu(h1 @ W2 + b2) = 34.4 GF bf16.
//
// k3 (R11): 256 blocks x 512 thr (8 waves, 1 block/CU). u-tile resident in regs;
// Bf[8][4] resident (static idx only -- rule #20). Per pair: 4 sub-batches of
// {4 ds_read (2 KS A-frags) -> 1 stage row-pass -> 16 MFMA} so reads + staging
// VALU run in the MFMA shadow (fixes intra-block phase serialization).
// vs is chunk-major [16][2][128] -> conflict-free b128 reads (was 8-way).
// h1 double-buffered (2x32KB, XOR-swizzled). One barrier per pair.

typedef float f32x4 __attribute__((ext_vector_type(4)));
typedef float f32x2 __attribute__((ext_vector_type(2)));
typedef short short8 __attribute__((ext_vector_type(8)));
typedef int   int4v  __attribute__((ext_vector_type(4)));

__device__ __forceinline__ uint32_t cvt_pk_bf16(float lo, float hi) {
    uint32_t r;
    asm("v_cvt_pk_bf16_f32 %0, %1, %2" : "=v"(r) : "v"(lo), "v"(hi));
    return r;
}
__device__ __forceinline__ f32x2 relu2(f32x2 a) {
    f32x2 z = (f32x2){0.f, 0.f};
    return __builtin_elementwise_max(a, z);
}

// K12: blocks 0..255: fused conv(8x8/s8)+relu+coords -> u,v rows.
//      blocks 256..287: pre-fragment W2 (bf16, fragment-major).
__global__ void k12_front(const float* __restrict__ img, const float* __restrict__ cw,
                          const float* __restrict__ cb, const float* __restrict__ w1,
                          const float* __restrict__ b1, const float* __restrict__ w2,
                          float* __restrict__ u, float* __restrict__ v,
                          short* __restrict__ w2f) {
    int g = blockIdx.x;
    int t = threadIdx.x;
    if (g >= 256) {
        int fi = (g - 256) * 4 + (t >> 6);
        int l = t & 63;
        int ks = fi >> 4, ni2 = fi & 15;
        int n  = ni2 * 16 + (l & 15);
        int k0 = ks * 32 + (l >> 4) * 8;
        float f[8];
        #pragma unroll
        for (int e = 0; e < 8; ++e) f[e] = w2[(k0 + e) * 256 + n];
        union { short8 s; uint32_t w[4]; } A;
        A.w[0] = cvt_pk_bf16(f[0], f[1]);
        A.w[1] = cvt_pk_bf16(f[2], f[3]);
        A.w[2] = cvt_pk_bf16(f[4], f[5]);
        A.w[3] = cvt_pk_bf16(f[6], f[7]);
        *(short8*)(w2f + (fi * 64 + l) * 8) = A.s;
        return;
    }
    __shared__ float xs[16][26];
    int b = g >> 2, q = g & 3, p0 = q * 16;

    for (int idx = t; idx < 416; idx += 256) {
        int pl = idx / 26;
        int ch = idx - pl * 26;
        int pos = p0 + pl;
        int r = pos >> 3, c = pos & 7;
        float val;
        if (ch < 24) {
            float s = cb[ch];
            #pragma unroll
            for (int ci = 0; ci < 3; ++ci)
                #pragma unroll
                for (int kr = 0; kr < 8; ++kr) {
                    const float* ip = img + ((b * 3 + ci) * 64 + r * 8 + kr) * 64 + c * 8;
                    const float* wp = cw + ((ch * 3 + ci) * 8 + kr) * 8;
                    #pragma unroll
                    for (int kc = 0; kc < 8; ++kc) s += ip[kc] * wp[kc];
                }
            val = fmaxf(s, 0.f);
        } else if (ch == 24) {
            val = -1.f + (2.f / 7.f) * (float)c;
        } else {
            val = -1.f + (2.f / 7.f) * (float)r;
        }
        xs[pl][ch] = val;
    }
    __syncthreads();

    // phase 2, k-outer (w1 loads hoisted)
    int c = t;
    float bc = b1[c];
    float su[16], sv[16];
    #pragma unroll
    for (int r = 0; r < 16; ++r) { su[r] = bc; sv[r] = 0.f; }
    #pragma unroll 2
    for (int k = 0; k < 26; ++k) {
        float wu = w1[k * 256 + c];
        float wv2 = w1[(26 + k) * 256 + c];
        #pragma unroll
        for (int r = 0; r < 16; ++r) {
            float xv = xs[r][k];
            su[r] += xv * wu;
            sv[r] += xv * wv2;
        }
    }
    #pragma unroll
    for (int r = 0; r < 16; ++r) {
        int bj = b * 64 + p0 + r;
        u[bj * 256 + c] = su[r];
        v[bj * 256 + c] = sv[r];
    }
}

// ---- k3 macros ----
// READ_A(KS): batch the 2 A-frags (mi=0,1) for slice KS into Aa/Ab[(KS)&1].
#define READ_A(KS)                                                    \
    { const char* hx = ((KS) & 1) ? hO : hE;                          \
      Aa[(KS) & 1] = *(const short8*)(hx + ((KS) >> 1) * 128);        \
      Ab[(KS) & 1] = *(const short8*)(hx + 8192 + ((KS) >> 1) * 128); }

#define MFMA_B(KS)                                                    \
    acc[0][0] = __builtin_amdgcn_mfma_f32_16x16x32_bf16(Aa[(KS)&1], Bf[KS][0], acc[0][0], 0, 0, 0); \
    acc[1][0] = __builtin_amdgcn_mfma_f32_16x16x32_bf16(Ab[(KS)&1], Bf[KS][0], acc[1][0], 0, 0, 0); \
    acc[0][1] = __builtin_amdgcn_mfma_f32_16x16x32_bf16(Aa[(KS)&1], Bf[KS][1], acc[0][1], 0, 0, 0); \
    acc[1][1] = __builtin_amdgcn_mfma_f32_16x16x32_bf16(Ab[(KS)&1], Bf[KS][1], acc[1][1], 0, 0, 0); \
    acc[0][2] = __builtin_amdgcn_mfma_f32_16x16x32_bf16(Aa[(KS)&1], Bf[KS][2], acc[0][2], 0, 0, 0); \
    acc[1][2] = __builtin_amdgcn_mfma_f32_16x16x32_bf16(Ab[(KS)&1], Bf[KS][2], acc[1][2], 0, 0, 0); \
    acc[0][3] = __builtin_amdgcn_mfma_f32_16x16x32_bf16(Aa[(KS)&1], Bf[KS][3], acc[0][3], 0, 0, 0); \
    acc[1][3] = __builtin_amdgcn_mfma_f32_16x16x32_bf16(Ab[(KS)&1], Bf[KS][3], acc[1][3], 0, 0, 0);

// PASS(RR): stage row rq*4+RR of next pair's h1 from u-regs + va/vb; ds_write_b128.
#define PASS(RR)                                                       \
    { f32x2 a0 = relu2((f32x2){u0[RR].x, u0[RR].y} + (f32x2){va.x, va.y}); \
      f32x2 a1 = relu2((f32x2){u0[RR].z, u0[RR].w} + (f32x2){va.z, va.w}); \
      f32x2 a2 = relu2((f32x2){u1[RR].x, u1[RR].y} + (f32x2){vb.x, vb.y}); \
      f32x2 a3 = relu2((f32x2){u1[RR].z, u1[RR].w} + (f32x2){vb.z, vb.w}); \
      int4v d;                                                         \
      d.x = (int)cvt_pk_bf16(a0.x, a0.y);                              \
      d.y = (int)cvt_pk_bf16(a1.x, a1.y);                              \
      d.z = (int)cvt_pk_bf16(a2.x, a2.y);                              \
      d.w = (int)cvt_pk_bf16(a3.x, a3.y);                              \
      *(int4v*)(wbuf + wb[RR]) = d; }

__global__ __launch_bounds__(512, 2) void k3_pairs(
        const float* __restrict__ u, const float* __restrict__ v,
        const short* __restrict__ w2f, const float* __restrict__ b2,
        float* __restrict__ part) {
    __shared__ short h1s[2][64 * 256];   // 64 KB
    __shared__ float vs[16][2][128];     // 16 KB, chunk-major (conflict-free)
    int t = threadIdx.x;
    int lane = t & 63, wv = t >> 6;      // wv 0..7
    int lr = lane & 15, lg = lane >> 4;
    int blk = blockIdx.x;                // 0..255
    int b = blk & 63, i0 = (blk >> 6) * 16;
    int r0 = (wv & 1) * 32;              // row half of C
    int c0 = (wv >> 1) * 64;             // col quarter of C

    // stage the 16 v rows once, chunk-major: vs[q][h][col8*4..+4]
    {
        int q = t >> 5, c8 = (t & 31) * 8;
        const float* vr = v + (b * 64 + i0 + q) * 256 + c8;
        *(float4*)&vs[q][0][(t & 31) * 4] = *(const float4*)vr;
        *(float4*)&vs[q][1][(t & 31) * 4] = *(const float4*)(vr + 4);
    }

    // resident B fragments: cols c0 + cg*16 (static indices only)
    short8 Bf[8][4];
    #pragma unroll
    for (int ks = 0; ks < 8; ++ks)
        #pragma unroll
        for (int cg = 0; cg < 4; ++cg)
            Bf[ks][cg] = *(const short8*)(w2f + ((ks * 16 + (wv >> 1) * 4 + cg) * 64 + lane) * 8);

    f32x2 bias2[4];
    #pragma unroll
    for (int cg = 0; cg < 4; ++cg) {
        float bv = b2[c0 + cg * 16 + lr];
        bias2[cg] = (f32x2){bv, bv};
    }

    // u residency: thread (col8 = t&31, rq = t>>5) holds rows rq*4..+4,
    // cols col8*8..+8 as f32 (32 VGPR)
    int col8 = t & 31, rq = t >> 5;
    const float* up = u + (b * 64 + rq * 4) * 256 + col8 * 8;
    f32x4 u0[4], u1[4];
    int wb[4];
    #pragma unroll
    for (int rr = 0; rr < 4; ++rr) {
        u0[rr] = *(const f32x4*)(up + rr * 256);
        u1[rr] = *(const f32x4*)(up + rr * 256 + 4);
        int row = rq * 4 + rr;
        wb[rr] = row * 512 + ((col8 * 16) ^ ((row & 7) << 4));
    }

    // read geometry
    int XB = (lg * 16) ^ ((lr & 7) << 4);
    int rE = (r0 + lr) * 512 + XB;
    int rO = (r0 + lr) * 512 + (XB ^ 64);

    __syncthreads();            // vs ready

    // prologue: stage pair 0 into buf 0
    {
        f32x4 va = *(const f32x4*)&vs[0][0][col8 * 4];
        f32x4 vb = *(const f32x4*)&vs[0][1][col8 * 4];
        char* wbuf = (char*)h1s[0];
        PASS(0) PASS(1) PASS(2) PASS(3)
    }
    __syncthreads();            // buf0 ready

    f32x2 csum2[4];
    #pragma unroll
    for (int cg = 0; cg < 4; ++cg) csum2[cg] = (f32x2){0.f, 0.f};

    #pragma unroll 1
    for (int q = 0; q < 16; ++q) {
        const char* hE = (const char*)h1s[q & 1] + rE;
        const char* hO = (const char*)h1s[q & 1] + rO;
        char* wbuf = (char*)h1s[(q + 1) & 1];
        bool pre = (q < 15);
        int qn = (q + 1) & 15;
        f32x4 va = *(const f32x4*)&vs[qn][0][col8 * 4];
        f32x4 vb = *(const f32x4*)&vs[qn][1][col8 * 4];

        f32x4 acc[2][4];
        #pragma unroll
        for (int mi = 0; mi < 2; ++mi)
            #pragma unroll
            for (int cg = 0; cg < 4; ++cg) acc[mi][cg] = (f32x4){0.f, 0.f, 0.f, 0.f};

        short8 Aa[2], Ab[2];

        READ_A(0) READ_A(1)
        if (pre) PASS(0)
        __builtin_amdgcn_s_setprio(1);
        MFMA_B(0) MFMA_B(1)
        __builtin_amdgcn_s_setprio(0);
        READ_A(2) READ_A(3)
        if (pre) PASS(1)
        __builtin_amdgcn_s_setprio(1);
        MFMA_B(2) MFMA_B(3)
        __builtin_amdgcn_s_setprio(0);
        READ_A(4) READ_A(5)
        if (pre) PASS(2)
        __builtin_amdgcn_s_setprio(1);
        MFMA_B(4) MFMA_B(5)
        __builtin_amdgcn_s_setprio(0);
        READ_A(6) READ_A(7)
        if (pre) PASS(3)
        __builtin_amdgcn_s_setprio(1);
        MFMA_B(6) MFMA_B(7)
        __builtin_amdgcn_s_setprio(0);

        // epilogue: relu(C + b2) partial column-sum (packed)
        #pragma unroll
        for (int cg = 0; cg < 4; ++cg) {
            #pragma unroll
            for (int mi = 0; mi < 2; ++mi) {
                f32x2 lo = relu2((f32x2){acc[mi][cg].x, acc[mi][cg].y} + bias2[cg]);
                f32x2 hi = relu2((f32x2){acc[mi][cg].z, acc[mi][cg].w} + bias2[cg]);
                csum2[cg] = csum2[cg] + lo + hi;
            }
        }
        __syncthreads();
    }

    // flush: reduce over lg groups; lanes 0-15 store this wave's 64-col partial
    #pragma unroll
    for (int cg = 0; cg < 4; ++cg) {
        float s = csum2[cg].x + csum2[cg].y;
        s += __shfl_xor(s, 16);
        s += __shfl_xor(s, 32);
        if (lane < 16) part[(blk * 8 + wv) * 64 + cg * 16 + lr] = s;
    }
}

// K5: pooled[b][c] = sum over 4 tiles x 2 row-half waves; then f-head.
__global__ void k5_head(const float* __restrict__ part, const float* __restrict__ fw1,
                        const float* __restrict__ fb1, const float* __restrict__ fw2,
                        const float* __restrict__ fb2, float* __restrict__ out) {
    __shared__ float P[256];
    __shared__ float wsum[4];
    int b = blockIdx.x, t = threadIdx.x;
    int wpair = (t >> 6) * 2, cl = t & 63;
    float s0 = 0.f;
    #pragma unroll
    for (int tile = 0; tile < 4; ++tile) {
        const float* p = part + (((b + 64 * tile) * 8) + wpair) * 64 + cl;
        s0 += p[0] + p[64];
    }
    P[t] = s0;
    __syncthreads();
    float a0 = 0.f, a1 = 0.f, a2 = 0.f, a3 = 0.f;
    for (int k = 0; k < 64; ++k) {
        a0 += P[k]       * fw1[k * 256 + t];
        a1 += P[k + 64]  * fw1[(k + 64) * 256 + t];
        a2 += P[k + 128] * fw1[(k + 128) * 256 + t];
        a3 += P[k + 192] * fw1[(k + 192) * 256 + t];
    }
    float h = fmaxf(fb1[t] + a0 + a1 + a2 + a3, 0.f);
    float p = h * fw2[t];
    #pragma unroll
    for (int off = 32; off >= 1; off >>= 1) p += __shfl_xor(p, off);
    if ((t & 63) == 0) wsum[t >> 6] = p;
    __syncthreads();
    if (t == 0) out[b] = wsum[0] + wsum[1] + wsum[2] + wsum[3] + fb2[0];
}

extern "C" void kernel_launch(void* const* d_in, const int* in_sizes, int n_in,
                              void* d_out, int out_size, void* d_ws, size_t ws_size,
                              hipStream_t stream) {
    const float* image  = (const float*)d_in[0];
    const float* conv_w = (const float*)d_in[1];
    const float* conv_b = (const float*)d_in[2];
    const float* g_w1   = (const float*)d_in[3];
    const float* g_b1   = (const float*)d_in[4];
    const float* g_w2   = (const float*)d_in[5];
    const float* g_b2   = (const float*)d_in[6];
    const float* f_w1   = (const float*)d_in[7];
    const float* f_b1   = (const float*)d_in[8];
    const float* f_w2   = (const float*)d_in[9];
    const float* f_b2   = (const float*)d_in[10];
    float* out = (float*)d_out;

    char* ws = (char*)d_ws;
    float* u    = (float*)(ws + 0);          // 64*64*256*4 = 4 MB
    float* v    = (float*)(ws + 4194304);    // 4 MB
    short* w2f  = (short*)(ws + 8388608);    // 128 KB
    float* part = (float*)(ws + 8519680);    // 256*8*64*4 = 512 KB

    k12_front<<<288, 256, 0, stream>>>(image, conv_w, conv_b, g_w1, g_b1, g_w2,
                                       u, v, w2f);
    k3_pairs<<<256, 512, 0, stream>>>(u, v, w2f, g_b2, part);
    k5_head<<<64, 256, 0, stream>>>(part, f_w1, f_b1, f_w2, f_b2, out);
}

// Round 12
// 60.301 us; speedup vs baseline: 1.0218x; 1.0122x over previous
//
#include <hip/hip_runtime.h>
#include <hip/hip_bf16.h>
#include <stdint.h>

// RNDiscriminator: B=64, d^2=64 positions, 26 features, g: 52->256->256, f: 256->1
// h1[i,j] = relu(u'[j] + v[i]); dominant cost sum_ij relu(h1 @ W2 + b2) = 34.4 GF bf16.
//
// k3 (R12): PRODUCER/CONSUMER WAVE SPECIALIZATION. 256 blocks x 512 thr, 1/CU.
// Waves 0-3 (one per SIMD): hold u-tile in regs, stage h1 pairs into a 4-deep
// LDS ring (32KB/slot, XOR-swizzled). Waves 4-7 (one per SIMD): hold Bf[8][4],
// pure ds_read+MFMA+colsum at setprio(1). NO __syncthreads in the pair loop --
// per-pair flag counters in LDS (release add / acquire spin). The consumer on
// each SIMD is never blocked by a block-wide phase change; matrix pipe stays fed.

typedef float f32x4 __attribute__((ext_vector_type(4)));
typedef float f32x2 __attribute__((ext_vector_type(2)));
typedef short short8 __attribute__((ext_vector_type(8)));
typedef int   int4v  __attribute__((ext_vector_type(4)));

#define NB 4   // ring depth

__device__ __forceinline__ uint32_t cvt_pk_bf16(float lo, float hi) {
    uint32_t r;
    asm("v_cvt_pk_bf16_f32 %0, %1, %2" : "=v"(r) : "v"(lo), "v"(hi));
    return r;
}
__device__ __forceinline__ f32x2 relu2(f32x2 a) {
    f32x2 z = (f32x2){0.f, 0.f};
    return __builtin_elementwise_max(a, z);
}
__device__ __forceinline__ void spin_eq(int* p, int val) {
    while (__hip_atomic_load(p, __ATOMIC_ACQUIRE, __HIP_MEMORY_SCOPE_WORKGROUP) != val)
        __builtin_amdgcn_s_sleep(1);
    __builtin_amdgcn_sched_barrier(0);
}
__device__ __forceinline__ void flag_release_add(int* p, int lane) {
    asm volatile("s_waitcnt lgkmcnt(0)" ::: "memory");   // prior LDS ops complete
    if (lane == 0)
        __hip_atomic_fetch_add(p, 1, __ATOMIC_RELEASE, __HIP_MEMORY_SCOPE_WORKGROUP);
}

// K12: blocks 0..255: fused conv(8x8/s8)+relu+coords -> u,v rows.
//      blocks 256..287: pre-fragment W2 (bf16, fragment-major).
__global__ void k12_front(const float* __restrict__ img, const float* __restrict__ cw,
                          const float* __restrict__ cb, const float* __restrict__ w1,
                          const float* __restrict__ b1, const float* __restrict__ w2,
                          float* __restrict__ u, float* __restrict__ v,
                          short* __restrict__ w2f) {
    int g = blockIdx.x;
    int t = threadIdx.x;
    if (g >= 256) {
        int fi = (g - 256) * 4 + (t >> 6);
        int l = t & 63;
        int ks = fi >> 4, ni2 = fi & 15;
        int n  = ni2 * 16 + (l & 15);
        int k0 = ks * 32 + (l >> 4) * 8;
        float f[8];
        #pragma unroll
        for (int e = 0; e < 8; ++e) f[e] = w2[(k0 + e) * 256 + n];
        union { short8 s; uint32_t w[4]; } A;
        A.w[0] = cvt_pk_bf16(f[0], f[1]);
        A.w[1] = cvt_pk_bf16(f[2], f[3]);
        A.w[2] = cvt_pk_bf16(f[4], f[5]);
        A.w[3] = cvt_pk_bf16(f[6], f[7]);
        *(short8*)(w2f + (fi * 64 + l) * 8) = A.s;
        return;
    }
    __shared__ float xs[16][26];
    int b = g >> 2, q = g & 3, p0 = q * 16;

    for (int idx = t; idx < 416; idx += 256) {
        int pl = idx / 26;
        int ch = idx - pl * 26;
        int pos = p0 + pl;
        int r = pos >> 3, c = pos & 7;
        float val;
        if (ch < 24) {
            float s = cb[ch];
            #pragma unroll
            for (int ci = 0; ci < 3; ++ci)
                #pragma unroll
                for (int kr = 0; kr < 8; ++kr) {
                    const float* ip = img + ((b * 3 + ci) * 64 + r * 8 + kr) * 64 + c * 8;
                    const float* wp = cw + ((ch * 3 + ci) * 8 + kr) * 8;
                    #pragma unroll
                    for (int kc = 0; kc < 8; ++kc) s += ip[kc] * wp[kc];
                }
            val = fmaxf(s, 0.f);
        } else if (ch == 24) {
            val = -1.f + (2.f / 7.f) * (float)c;
        } else {
            val = -1.f + (2.f / 7.f) * (float)r;
        }
        xs[pl][ch] = val;
    }
    __syncthreads();

    // phase 2, k-outer (w1 loads hoisted)
    int c = t;
    float bc = b1[c];
    float su[16], sv[16];
    #pragma unroll
    for (int r = 0; r < 16; ++r) { su[r] = bc; sv[r] = 0.f; }
    #pragma unroll 2
    for (int k = 0; k < 26; ++k) {
        float wu = w1[k * 256 + c];
        float wv2 = w1[(26 + k) * 256 + c];
        #pragma unroll
        for (int r = 0; r < 16; ++r) {
            float xv = xs[r][k];
            su[r] += xv * wu;
            sv[r] += xv * wv2;
        }
    }
    #pragma unroll
    for (int r = 0; r < 16; ++r) {
        int bj = b * 64 + p0 + r;
        u[bj * 256 + c] = su[r];
        v[bj * 256 + c] = sv[r];
    }
}

// ---- k3 consumer macros ----
// A-frag (row = mi*16+lr, ks): byte = mi*8192 + lr*512 + (ks>>1)*128 + (XB [^64 odd ks])
#define C_READ(A, KS)                                                  \
    { const char* hx = ((KS) & 1) ? hO : hE;                           \
      A[0] = *(const short8*)(hx + ((KS) >> 1) * 128);                 \
      A[1] = *(const short8*)(hx + 8192  + ((KS) >> 1) * 128);         \
      A[2] = *(const short8*)(hx + 16384 + ((KS) >> 1) * 128);         \
      A[3] = *(const short8*)(hx + 24576 + ((KS) >> 1) * 128); }

#define C_MFMA(A, KS)                                                  \
    { acc[0][0] = __builtin_amdgcn_mfma_f32_16x16x32_bf16(A[0], Bf[KS][0], acc[0][0], 0,0,0); \
      acc[1][0] = __builtin_amdgcn_mfma_f32_16x16x32_bf16(A[1], Bf[KS][0], acc[1][0], 0,0,0); \
      acc[2][0] = __builtin_amdgcn_mfma_f32_16x16x32_bf16(A[2], Bf[KS][0], acc[2][0], 0,0,0); \
      acc[3][0] = __builtin_amdgcn_mfma_f32_16x16x32_bf16(A[3], Bf[KS][0], acc[3][0], 0,0,0); \
      acc[0][1] = __builtin_amdgcn_mfma_f32_16x16x32_bf16(A[0], Bf[KS][1], acc[0][1], 0,0,0); \
      acc[1][1] = __builtin_amdgcn_mfma_f32_16x16x32_bf16(A[1], Bf[KS][1], acc[1][1], 0,0,0); \
      acc[2][1] = __builtin_amdgcn_mfma_f32_16x16x32_bf16(A[2], Bf[KS][1], acc[2][1], 0,0,0); \
      acc[3][1] = __builtin_amdgcn_mfma_f32_16x16x32_bf16(A[3], Bf[KS][1], acc[3][1], 0,0,0); \
      acc[0][2] = __builtin_amdgcn_mfma_f32_16x16x32_bf16(A[0], Bf[KS][2], acc[0][2], 0,0,0); \
      acc[1][2] = __builtin_amdgcn_mfma_f32_16x16x32_bf16(A[1], Bf[KS][2], acc[1][2], 0,0,0); \
      acc[2][2] = __builtin_amdgcn_mfma_f32_16x16x32_bf16(A[2], Bf[KS][2], acc[2][2], 0,0,0); \
      acc[3][2] = __builtin_amdgcn_mfma_f32_16x16x32_bf16(A[3], Bf[KS][2], acc[3][2], 0,0,0); \
      acc[0][3] = __builtin_amdgcn_mfma_f32_16x16x32_bf16(A[0], Bf[KS][3], acc[0][3], 0,0,0); \
      acc[1][3] = __builtin_amdgcn_mfma_f32_16x16x32_bf16(A[1], Bf[KS][3], acc[1][3], 0,0,0); \
      acc[2][3] = __builtin_amdgcn_mfma_f32_16x16x32_bf16(A[2], Bf[KS][3], acc[2][3], 0,0,0); \
      acc[3][3] = __builtin_amdgcn_mfma_f32_16x16x32_bf16(A[3], Bf[KS][3], acc[3][3], 0,0,0); }

__global__ __launch_bounds__(512, 2) void k3_pairs(
        const float* __restrict__ u, const float* __restrict__ v,
        const short* __restrict__ w2f, const float* __restrict__ b2,
        float* __restrict__ part) {
    __shared__ short h1s[NB][64 * 256];   // 4 x 32 KB ring
    __shared__ float vs[16][2][128];      // 16 KB, chunk-major
    __shared__ int prod_cnt[16];
    __shared__ int cons_cnt[16];
    int t = threadIdx.x;
    int lane = t & 63, wv = t >> 6;
    int blk = blockIdx.x;                 // 0..255
    int b = blk & 63, i0 = (blk >> 6) * 16;

    if (t < 16) { prod_cnt[t] = 0; cons_cnt[t] = 0; }

    // stage the 16 v rows once, chunk-major (all 512 threads)
    {
        int q = t >> 5, c8 = (t & 31) * 8;
        const float* vr = v + (b * 64 + i0 + q) * 256 + c8;
        *(float4*)&vs[q][0][(t & 31) * 4] = *(const float4*)vr;
        *(float4*)&vs[q][1][(t & 31) * 4] = *(const float4*)(vr + 4);
    }
    __syncthreads();

    if (wv < 4) {
        // ================= PRODUCER (waves 0-3, one per SIMD) =================
        // thread (col8 = t&31, rq = t>>5): rows rq*8..+8, bf16 cols col8*8..+8
        int col8 = t & 31, rq = t >> 5;   // t in 0..255
        const float* up = u + (b * 64 + rq * 8) * 256 + col8 * 8;
        f32x4 u0[8], u1[8];
        #pragma unroll
        for (int rr = 0; rr < 8; ++rr) {
            u0[rr] = *(const f32x4*)(up + rr * 256);
            u1[rr] = *(const f32x4*)(up + rr * 256 + 4);
        }
        int wbase = rq * 8 * 512;
        int c16 = col8 * 16;

        #pragma unroll 1
        for (int q = 0; q < 16; ++q) {
            if (q >= NB) spin_eq(&cons_cnt[q - NB], 4);
            char* wbuf = (char*)h1s[q & (NB - 1)] + wbase;
            f32x4 va = *(const f32x4*)&vs[q][0][col8 * 4];
            f32x4 vb = *(const f32x4*)&vs[q][1][col8 * 4];
            #pragma unroll
            for (int rr = 0; rr < 8; ++rr) {   // row = rq*8+rr, row&7 == rr
                f32x2 a0 = relu2((f32x2){u0[rr].x, u0[rr].y} + (f32x2){va.x, va.y});
                f32x2 a1 = relu2((f32x2){u0[rr].z, u0[rr].w} + (f32x2){va.z, va.w});
                f32x2 a2 = relu2((f32x2){u1[rr].x, u1[rr].y} + (f32x2){vb.x, vb.y});
                f32x2 a3 = relu2((f32x2){u1[rr].z, u1[rr].w} + (f32x2){vb.z, vb.w});
                int4v d;
                d.x = (int)cvt_pk_bf16(a0.x, a0.y);
                d.y = (int)cvt_pk_bf16(a1.x, a1.y);
                d.z = (int)cvt_pk_bf16(a2.x, a2.y);
                d.w = (int)cvt_pk_bf16(a3.x, a3.y);
                *(int4v*)(wbuf + rr * 512 + (c16 ^ (rr << 4))) = d;
            }
            flag_release_add(&prod_cnt[q], lane);
        }
    } else {
        // ================= CONSUMER (waves 4-7, one per SIMD) =================
        int wc = wv - 4;                  // col quarter: cols wc*64..+64
        int lr = lane & 15, lg = lane >> 4;

        short8 Bf[8][4];
        #pragma unroll
        for (int ks = 0; ks < 8; ++ks)
            #pragma unroll
            for (int cg = 0; cg < 4; ++cg)
                Bf[ks][cg] = *(const short8*)(w2f + ((ks * 16 + wc * 4 + cg) * 64 + lane) * 8);

        f32x2 bias2[4];
        #pragma unroll
        for (int cg = 0; cg < 4; ++cg) {
            float bv = b2[wc * 64 + cg * 16 + lr];
            bias2[cg] = (f32x2){bv, bv};
        }

        int XB = (lg * 16) ^ ((lr & 7) << 4);
        int rE0 = lr * 512 + XB;
        int rO0 = lr * 512 + (XB ^ 64);

        f32x2 csum2[4];
        #pragma unroll
        for (int cg = 0; cg < 4; ++cg) csum2[cg] = (f32x2){0.f, 0.f};

        __builtin_amdgcn_s_setprio(1);
        #pragma unroll 1
        for (int q = 0; q < 16; ++q) {
            spin_eq(&prod_cnt[q], 4);
            const char* base = (const char*)h1s[q & (NB - 1)];
            const char* hE = base + rE0;
            const char* hO = base + rO0;

            f32x4 acc[4][4];
            #pragma unroll
            for (int mi = 0; mi < 4; ++mi)
                #pragma unroll
                for (int cg = 0; cg < 4; ++cg) acc[mi][cg] = (f32x4){0.f, 0.f, 0.f, 0.f};

            short8 Aa[4], Ab[4];
            C_READ(Aa, 0) C_READ(Ab, 1)
            C_MFMA(Aa, 0) C_READ(Aa, 2)
            C_MFMA(Ab, 1) C_READ(Ab, 3)
            C_MFMA(Aa, 2) C_READ(Aa, 4)
            C_MFMA(Ab, 3) C_READ(Ab, 5)
            C_MFMA(Aa, 4) C_READ(Aa, 6)
            C_MFMA(Ab, 5) C_READ(Ab, 7)
            C_MFMA(Aa, 6)
            C_MFMA(Ab, 7)

            // epilogue: relu(C + b2) partial column-sum (packed)
            #pragma unroll
            for (int cg = 0; cg < 4; ++cg) {
                #pragma unroll
                for (int mi = 0; mi < 4; ++mi) {
                    f32x2 lo = relu2((f32x2){acc[mi][cg].x, acc[mi][cg].y} + bias2[cg]);
                    f32x2 hi = relu2((f32x2){acc[mi][cg].z, acc[mi][cg].w} + bias2[cg]);
                    csum2[cg] = csum2[cg] + lo + hi;
                }
            }
            flag_release_add(&cons_cnt[q], lane);
        }
        __builtin_amdgcn_s_setprio(0);

        // flush: reduce over lg groups; lanes 0-15 store this wave's 64-col partial
        #pragma unroll
        for (int cg = 0; cg < 4; ++cg) {
            float s = csum2[cg].x + csum2[cg].y;
            s += __shfl_xor(s, 16);
            s += __shfl_xor(s, 32);
            if (lane < 16) part[(blk * 4 + wc) * 64 + cg * 16 + lr] = s;
        }
    }
}

// K5: pooled[b][c] = sum over 4 i-tiles of part[((b+64g)*4 + wc)*64 + cl]; then f-head.
__global__ void k5_head(const float* __restrict__ part, const float* __restrict__ fw1,
                        const float* __restrict__ fb1, const float* __restrict__ fw2,
                        const float* __restrict__ fb2, float* __restrict__ out) {
    __shared__ float P[256];
    __shared__ float wsum[4];
    int b = blockIdx.x, t = threadIdx.x;
    int wc = t >> 6, cl = t & 63;
    float s0 = 0.f;
    #pragma unroll
    for (int g = 0; g < 4; ++g)
        s0 += part[((b + 64 * g) * 4 + wc) * 64 + cl];
    P[t] = s0;
    __syncthreads();
    float a0 = 0.f, a1 = 0.f, a2 = 0.f, a3 = 0.f;
    for (int k = 0; k < 64; ++k) {
        a0 += P[k]       * fw1[k * 256 + t];
        a1 += P[k + 64]  * fw1[(k + 64) * 256 + t];
        a2 += P[k + 128] * fw1[(k + 128) * 256 + t];
        a3 += P[k + 192] * fw1[(k + 192) * 256 + t];
    }
    float h = fmaxf(fb1[t] + a0 + a1 + a2 + a3, 0.f);
    float p = h * fw2[t];
    #pragma unroll
    for (int off = 32; off >= 1; off >>= 1) p += __shfl_xor(p, off);
    if ((t & 63) == 0) wsum[t >> 6] = p;
    __syncthreads();
    if (t == 0) out[b] = wsum[0] + wsum[1] + wsum[2] + wsum[3] + fb2[0];
}

extern "C" void kernel_launch(void* const* d_in, const int* in_sizes, int n_in,
                              void* d_out, int out_size, void* d_ws, size_t ws_size,
                              hipStream_t stream) {
    const float* image  = (const float*)d_in[0];
    const float* conv_w = (const float*)d_in[1];
    const float* conv_b = (const float*)d_in[2];
    const float* g_w1   = (const float*)d_in[3];
    const float* g_b1   = (const float*)d_in[4];
    const float* g_w2   = (const float*)d_in[5];
    const float* g_b2   = (const float*)d_in[6];
    const float* f_w1   = (const float*)d_in[7];
    const float* f_b1   = (const float*)d_in[8];
    const float* f_w2   = (const float*)d_in[9];
    const float* f_b2   = (const float*)d_in[10];
    float* out = (float*)d_out;

    char* ws = (char*)d_ws;
    float* u    = (float*)(ws + 0);          // 64*64*256*4 = 4 MB
    float* v    = (float*)(ws + 4194304);    // 4 MB
    short* w2f  = (short*)(ws + 8388608);    // 128 KB
    float* part = (float*)(ws + 8519680);    // 256*4*64*4 = 256 KB

    k12_front<<<288, 256, 0, stream>>>(image, conv_w, conv_b, g_w1, g_b1, g_w2,
                                       u, v, w2f);
    k3_pairs<<<256, 512, 0, stream>>>(u, v, w2f, g_b2, part);
    k5_head<<<64, 256, 0, stream>>>(part, f_w1, f_b1, f_w2, f_b2, out);
}